// Round 1
// baseline (368.314 us; speedup 1.0000x reference)
//
#include <hip/hip_runtime.h>

// VarlenAttention on MI355X — round 1: correct flash-style vector-fp32 kernel.
// One block = 32-query tile x 1 head, 256 threads (4 waves).
constexpr int NSEG = 8;   // B segments
constexpr int H    = 16;
constexpr int D    = 64;
constexpr int BQ   = 32;
constexpr int BK   = 32;
constexpr int NT   = 256;

__global__ __launch_bounds__(NT)
void varlen_attn(const float* __restrict__ Q, const float* __restrict__ K,
                 const float* __restrict__ V, const int* __restrict__ cuq,
                 const int* __restrict__ cuk, float* __restrict__ O, int T)
{
    __shared__ float sQ[BQ][D];          // 8 KB
    __shared__ float sKT[D][BK + 1];     // transposed K chunk, +1 pad: conflict-free
    __shared__ float sV[BK][D];          // 8 KB
    __shared__ float sS[BQ][BK + 1];     // scores/probs, +1 pad
    __shared__ float sM[BQ], sL[BQ], sAlpha[BQ];
    __shared__ int   sSegQ[BQ];
    __shared__ int   sSegK[BK];
    __shared__ int   sCuQ[NSEG + 1], sCuK[NSEG + 1];

    const int tid = threadIdx.x;
    const int h  = blockIdx.x % H;
    const int t0 = (blockIdx.x / H) * BQ;

    if (tid <= NSEG) { sCuQ[tid] = cuq[tid]; sCuK[tid] = cuk[tid]; }
    __syncthreads();

    // stage Q tile (coalesced float4)
    for (int i = tid; i < BQ * D / 4; i += NT) {
        int r = i / (D / 4);
        int c = (i % (D / 4)) * 4;
        int tq = t0 + r; if (tq >= T) tq = T - 1;
        *(float4*)&sQ[r][c] = *(const float4*)&Q[((size_t)tq * H + h) * D + c];
    }
    if (tid < BQ) {
        int t = t0 + tid; if (t >= T) t = T - 1;
        int s = 0;
        while (s < NSEG - 1 && t >= sCuQ[s + 1]) ++s;   // searchsorted(cu[1:], t, right)
        sSegQ[tid] = s;
        sM[tid] = -1e30f;
        sL[tid] = 0.0f;
    }
    __syncthreads();

    const int k_start = sCuK[sSegQ[0]];
    const int k_end   = sCuK[sSegQ[BQ - 1] + 1];

    // score-phase mapping: 1 col x 4 rows per thread
    const int scol  = tid & 31;
    const int srow0 = (tid >> 5) * 4;
    int qseg[4];
    #pragma unroll
    for (int rr = 0; rr < 4; ++rr) qseg[rr] = sSegQ[srow0 + rr];

    // softmax-phase mapping: 8 lanes per row, 4 entries each
    const int smrow = tid >> 3;
    const int smj   = (tid & 7) * 4;

    // PV/output mapping: row = tid>>3, 8 dims starting at (tid&7)*8
    const int prow = tid >> 3;
    const int pdc  = (tid & 7) * 8;

    float acc[8];
    #pragma unroll
    for (int j = 0; j < 8; ++j) acc[j] = 0.0f;

    const float scale = 0.125f;  // 1/sqrt(64)

    for (int kc = k_start; kc < k_end; kc += BK) {
        __syncthreads();  // previous PV done with sV/sS

        // stage K (transposed) + V, zero-fill out-of-range (avoids NaN via p*V)
        for (int i = tid; i < BK * D / 4; i += NT) {
            int r = i >> 4;            // 16 float4 per 64-dim row
            int c = (i & 15) * 4;
            int kt = kc + r;
            float4 kv = {0.f, 0.f, 0.f, 0.f}, vv = {0.f, 0.f, 0.f, 0.f};
            if (kt < k_end) {
                kv = *(const float4*)&K[((size_t)kt * H + h) * D + c];
                vv = *(const float4*)&V[((size_t)kt * H + h) * D + c];
            }
            sKT[c + 0][r] = kv.x;
            sKT[c + 1][r] = kv.y;
            sKT[c + 2][r] = kv.z;
            sKT[c + 3][r] = kv.w;
            *(float4*)&sV[r][c] = vv;
        }
        if (tid < BK) {
            int kt = kc + tid;
            int s = -1;                // -1 => invalid key, never matches qseg
            if (kt < k_end) {
                s = 0;
                while (s < NSEG - 1 && kt >= sCuK[s + 1]) ++s;
            }
            sSegK[tid] = s;
        }
        __syncthreads();

        // QK^T: 4 scores per thread
        float sc[4] = {0.f, 0.f, 0.f, 0.f};
        for (int d4 = 0; d4 < D; d4 += 4) {
            float k0 = sKT[d4 + 0][scol];
            float k1 = sKT[d4 + 1][scol];
            float k2 = sKT[d4 + 2][scol];
            float k3 = sKT[d4 + 3][scol];
            #pragma unroll
            for (int rr = 0; rr < 4; ++rr) {
                float4 q4 = *(float4*)&sQ[srow0 + rr][d4];
                sc[rr] = fmaf(q4.x, k0, sc[rr]);
                sc[rr] = fmaf(q4.y, k1, sc[rr]);
                sc[rr] = fmaf(q4.z, k2, sc[rr]);
                sc[rr] = fmaf(q4.w, k3, sc[rr]);
            }
        }
        {
            int kseg = sSegK[scol];
            #pragma unroll
            for (int rr = 0; rr < 4; ++rr)
                sS[srow0 + rr][scol] = (kseg == qseg[rr]) ? sc[rr] * scale : -1e30f;
        }
        __syncthreads();

        // online softmax: 8 lanes cooperate per row
        {
            float s0 = sS[smrow][smj + 0];
            float s1 = sS[smrow][smj + 1];
            float s2 = sS[smrow][smj + 2];
            float s3 = sS[smrow][smj + 3];
            float mx = fmaxf(fmaxf(s0, s1), fmaxf(s2, s3));
            #pragma unroll
            for (int off = 1; off < 8; off <<= 1)
                mx = fmaxf(mx, __shfl_xor(mx, off));
            float m_old = sM[smrow];
            float m_new = fmaxf(m_old, mx);
            float alpha = __expf(m_old - m_new);
            // guard: fully-masked entries must contribute p=0 (not exp(0)=1)
            float p0 = (s0 > -1e29f) ? __expf(s0 - m_new) : 0.f;
            float p1 = (s1 > -1e29f) ? __expf(s1 - m_new) : 0.f;
            float p2 = (s2 > -1e29f) ? __expf(s2 - m_new) : 0.f;
            float p3 = (s3 > -1e29f) ? __expf(s3 - m_new) : 0.f;
            sS[smrow][smj + 0] = p0;
            sS[smrow][smj + 1] = p1;
            sS[smrow][smj + 2] = p2;
            sS[smrow][smj + 3] = p3;
            float sum = (p0 + p1) + (p2 + p3);
            #pragma unroll
            for (int off = 1; off < 8; off <<= 1)
                sum += __shfl_xor(sum, off);
            if ((tid & 7) == 0) {
                sM[smrow] = m_new;
                sL[smrow] = sL[smrow] * alpha + sum;
                sAlpha[smrow] = alpha;
            }
        }
        __syncthreads();

        // rescale accumulator + PV
        {
            float a = sAlpha[prow];
            #pragma unroll
            for (int j = 0; j < 8; ++j) acc[j] *= a;
            for (int kk = 0; kk < BK; ++kk) {
                float p = sS[prow][kk];
                float4 v0 = *(float4*)&sV[kk][pdc];
                float4 v1 = *(float4*)&sV[kk][pdc + 4];
                acc[0] = fmaf(p, v0.x, acc[0]);
                acc[1] = fmaf(p, v0.y, acc[1]);
                acc[2] = fmaf(p, v0.z, acc[2]);
                acc[3] = fmaf(p, v0.w, acc[3]);
                acc[4] = fmaf(p, v1.x, acc[4]);
                acc[5] = fmaf(p, v1.y, acc[5]);
                acc[6] = fmaf(p, v1.z, acc[6]);
                acc[7] = fmaf(p, v1.w, acc[7]);
            }
        }
    }

    // epilogue: normalize and store (sL last written before the pre-PV sync)
    if (t0 + prow < T) {
        float linv = 1.0f / sL[prow];
        size_t base = ((size_t)(t0 + prow) * H + h) * D + pdc;
        float4 o0 = {acc[0] * linv, acc[1] * linv, acc[2] * linv, acc[3] * linv};
        float4 o1 = {acc[4] * linv, acc[5] * linv, acc[6] * linv, acc[7] * linv};
        *(float4*)&O[base] = o0;
        *(float4*)&O[base + 4] = o1;
    }
}

extern "C" void kernel_launch(void* const* d_in, const int* in_sizes, int n_in,
                              void* d_out, int out_size, void* d_ws, size_t ws_size,
                              hipStream_t stream) {
    const float* Q = (const float*)d_in[0];
    const float* K = (const float*)d_in[1];
    const float* V = (const float*)d_in[2];
    const int* cuq = (const int*)d_in[3];
    const int* cuk = (const int*)d_in[4];
    float* O = (float*)d_out;

    int T = in_sizes[0] / (H * D);
    int nQT = (T + BQ - 1) / BQ;
    dim3 grid(nQT * H), block(NT);
    hipLaunchKernelGGL(varlen_attn, grid, block, 0, stream, Q, K, V, cuq, cuk, O, T);
}

// Round 2
// 169.665 us; speedup vs baseline: 2.1708x; 2.1708x over previous
//
#include <hip/hip_runtime.h>

// VarlenAttention MI355X — round 2: flash-style bf16 MFMA kernel.
// Block = 64 q-rows x 1 head, 256 threads (4 waves, 16 q-rows per wave).
constexpr int NSEG = 8;
constexpr int H    = 16;
constexpr int D    = 64;
constexpr int BQ   = 64;   // q rows per block
constexpr int BK   = 64;   // keys per chunk
constexpr int NT   = 256;
constexpr int LDK  = D  + 8;   // sK row stride (shorts): 144B, 16B-aligned rows
constexpr int LDV  = BK + 8;   // sVT row stride
constexpr int LDP  = BK + 8;   // sP row stride

typedef __attribute__((ext_vector_type(8))) short short8v;
typedef __attribute__((ext_vector_type(4))) short short4v;
typedef __attribute__((ext_vector_type(4))) float floatx4;

__device__ inline short f2bf(float f) {  // RNE fp32 -> bf16
    union { float f; unsigned u; } x; x.f = f;
    unsigned r = x.u + 0x7FFFu + ((x.u >> 16) & 1u);
    return (short)(r >> 16);
}

__global__ __launch_bounds__(NT)
void varlen_attn_mfma(const float* __restrict__ Q, const float* __restrict__ K,
                      const float* __restrict__ V, const int* __restrict__ cuq,
                      const int* __restrict__ cuk, float* __restrict__ O, int T)
{
    __shared__ short sK[BK][LDK];        // K chunk, row-major (key, d), bf16
    __shared__ short sVT[D][LDV];        // V chunk transposed (d, key), bf16
    __shared__ short sP[4][16][LDP];     // per-wave P tile (qrow, key), bf16
    __shared__ int   sSegK[BK];
    __shared__ int   sCuQ[NSEG + 1], sCuK[NSEG + 1];

    const int tid  = threadIdx.x;
    const int lane = tid & 63;
    const int w    = tid >> 6;
    const int quad = lane >> 4;
    const int l15  = lane & 15;
    const int h    = blockIdx.x % H;
    const int t0   = (blockIdx.x / H) * BQ;

    if (tid <= NSEG) { sCuQ[tid] = cuq[tid]; sCuK[tid] = cuk[tid]; }
    __syncthreads();

    // ---- Q A-fragments, loaded once, pre-scaled by 1/sqrt(64)=0.125 (exact in bf16)
    int qrow = t0 + 16 * w + l15; if (qrow >= T) qrow = T - 1;
    const float* qp = Q + ((size_t)qrow * H + h) * D + quad * 8;
    short8v aQ0, aQ1;
    {
        float4 q0 = *(const float4*)(qp);
        float4 q1 = *(const float4*)(qp + 4);
        float4 q2 = *(const float4*)(qp + 32);
        float4 q3 = *(const float4*)(qp + 36);
        aQ0[0] = f2bf(q0.x * 0.125f); aQ0[1] = f2bf(q0.y * 0.125f);
        aQ0[2] = f2bf(q0.z * 0.125f); aQ0[3] = f2bf(q0.w * 0.125f);
        aQ0[4] = f2bf(q1.x * 0.125f); aQ0[5] = f2bf(q1.y * 0.125f);
        aQ0[6] = f2bf(q1.z * 0.125f); aQ0[7] = f2bf(q1.w * 0.125f);
        aQ1[0] = f2bf(q2.x * 0.125f); aQ1[1] = f2bf(q2.y * 0.125f);
        aQ1[2] = f2bf(q2.z * 0.125f); aQ1[3] = f2bf(q2.w * 0.125f);
        aQ1[4] = f2bf(q3.x * 0.125f); aQ1[5] = f2bf(q3.y * 0.125f);
        aQ1[6] = f2bf(q3.z * 0.125f); aQ1[7] = f2bf(q3.w * 0.125f);
    }

    // ---- per-reg q segment ids (C/D layout rows: quad*4 + r)
    int segq[4];
    #pragma unroll
    for (int r = 0; r < 4; ++r) {
        int t = t0 + 16 * w + quad * 4 + r; if (t >= T) t = T - 1;
        int s = 0;
        while (s < NSEG - 1 && t >= sCuQ[s + 1]) ++s;
        segq[r] = s;
    }

    int k_start, k_end;
    {
        int tA = t0; if (tA >= T) tA = T - 1;
        int tB = t0 + BQ - 1; if (tB >= T) tB = T - 1;
        int sA = 0; while (sA < NSEG - 1 && tA >= sCuQ[sA + 1]) ++sA;
        int sB = 0; while (sB < NSEG - 1 && tB >= sCuQ[sB + 1]) ++sB;
        k_start = sCuK[sA];
        k_end   = sCuK[sB + 1];
    }

    floatx4 o[4];
    #pragma unroll
    for (int nt = 0; nt < 4; ++nt) o[nt] = (floatx4){0.f, 0.f, 0.f, 0.f};
    float m_r[4], l_r[4];
    #pragma unroll
    for (int r = 0; r < 4; ++r) { m_r[r] = -1e30f; l_r[r] = 0.f; }

    for (int kc = k_start; kc < k_end; kc += BK) {
        __syncthreads();   // previous chunk's sK/sVT reads complete

        // ---- stage K (row-major) + V (transposed), fp32 -> bf16, zero-fill OOR
        for (int i = tid; i < BK * D / 4; i += NT) {
            int k = i >> 4;
            int c = (i & 15) << 2;
            int kt = kc + k;
            float4 kv = {0.f, 0.f, 0.f, 0.f}, vv = {0.f, 0.f, 0.f, 0.f};
            if (kt < k_end) {
                kv = *(const float4*)&K[((size_t)kt * H + h) * D + c];
                vv = *(const float4*)&V[((size_t)kt * H + h) * D + c];
            }
            short4v ks;
            ks.x = f2bf(kv.x); ks.y = f2bf(kv.y); ks.z = f2bf(kv.z); ks.w = f2bf(kv.w);
            *(short4v*)&sK[k][c] = ks;
            sVT[c + 0][k] = f2bf(vv.x);
            sVT[c + 1][k] = f2bf(vv.y);
            sVT[c + 2][k] = f2bf(vv.z);
            sVT[c + 3][k] = f2bf(vv.w);
        }
        if (tid < BK) {
            int kt = kc + tid;
            int s = -1;
            if (kt < k_end) { s = 0; while (s < NSEG - 1 && kt >= sCuK[s + 1]) ++s; }
            sSegK[tid] = s;
        }
        __syncthreads();

        // ---- S = Q K^T via MFMA (4 col-tiles x K=64)
        floatx4 sacc[4];
        #pragma unroll
        for (int nt = 0; nt < 4; ++nt) {
            sacc[nt] = (floatx4){0.f, 0.f, 0.f, 0.f};
            short8v b0 = *(const short8v*)&sK[nt * 16 + l15][quad * 8];
            short8v b1 = *(const short8v*)&sK[nt * 16 + l15][32 + quad * 8];
            sacc[nt] = __builtin_amdgcn_mfma_f32_16x16x32_bf16(aQ0, b0, sacc[nt], 0, 0, 0);
            sacc[nt] = __builtin_amdgcn_mfma_f32_16x16x32_bf16(aQ1, b1, sacc[nt], 0, 0, 0);
        }

        // ---- mask + online softmax (register/C-layout, 16-lane row reductions)
        int segk[4];
        #pragma unroll
        for (int nt = 0; nt < 4; ++nt) segk[nt] = sSegK[nt * 16 + l15];

        float sc[4][4];
        #pragma unroll
        for (int nt = 0; nt < 4; ++nt)
            #pragma unroll
            for (int r = 0; r < 4; ++r)
                sc[nt][r] = (segk[nt] == segq[r]) ? sacc[nt][r] : -1e30f;

        float mx[4];
        #pragma unroll
        for (int r = 0; r < 4; ++r)
            mx[r] = fmaxf(fmaxf(sc[0][r], sc[1][r]), fmaxf(sc[2][r], sc[3][r]));
        #pragma unroll
        for (int off = 1; off < 16; off <<= 1)
            #pragma unroll
            for (int r = 0; r < 4; ++r)
                mx[r] = fmaxf(mx[r], __shfl_xor(mx[r], off));

        float alpha[4];
        #pragma unroll
        for (int r = 0; r < 4; ++r) {
            float m_new = fmaxf(m_r[r], mx[r]);
            alpha[r] = __expf(m_r[r] - m_new);
            m_r[r] = m_new;
        }

        float psum[4] = {0.f, 0.f, 0.f, 0.f};
        #pragma unroll
        for (int nt = 0; nt < 4; ++nt)
            #pragma unroll
            for (int r = 0; r < 4; ++r) {
                float p = (sc[nt][r] > -1e29f) ? __expf(sc[nt][r] - m_r[r]) : 0.f;
                psum[r] += p;
                sP[w][quad * 4 + r][nt * 16 + l15] = f2bf(p);
            }
        #pragma unroll
        for (int off = 1; off < 16; off <<= 1)
            #pragma unroll
            for (int r = 0; r < 4; ++r)
                psum[r] += __shfl_xor(psum[r], off);
        #pragma unroll
        for (int r = 0; r < 4; ++r)
            l_r[r] = l_r[r] * alpha[r] + psum[r];

        #pragma unroll
        for (int nt = 0; nt < 4; ++nt)
            #pragma unroll
            for (int r = 0; r < 4; ++r)
                o[nt][r] *= alpha[r];

        // ---- O += P V  (A from own sP region — in-wave LDS roundtrip, no barrier)
        short8v aP0 = *(const short8v*)&sP[w][l15][quad * 8];
        short8v aP1 = *(const short8v*)&sP[w][l15][32 + quad * 8];
        #pragma unroll
        for (int nt = 0; nt < 4; ++nt) {
            short8v b0 = *(const short8v*)&sVT[nt * 16 + l15][quad * 8];
            short8v b1 = *(const short8v*)&sVT[nt * 16 + l15][32 + quad * 8];
            o[nt] = __builtin_amdgcn_mfma_f32_16x16x32_bf16(aP0, b0, o[nt], 0, 0, 0);
            o[nt] = __builtin_amdgcn_mfma_f32_16x16x32_bf16(aP1, b1, o[nt], 0, 0, 0);
        }
    }

    // ---- epilogue: normalize, store (C layout: row=quad*4+r, col=l15)
    #pragma unroll
    for (int r = 0; r < 4; ++r) {
        int trow = t0 + 16 * w + quad * 4 + r;
        if (trow < T) {
            float linv = 1.0f / l_r[r];
            float* op = O + ((size_t)trow * H + h) * D + l15;
            #pragma unroll
            for (int nt = 0; nt < 4; ++nt)
                op[nt * 16] = o[nt][r] * linv;
        }
    }
}

extern "C" void kernel_launch(void* const* d_in, const int* in_sizes, int n_in,
                              void* d_out, int out_size, void* d_ws, size_t ws_size,
                              hipStream_t stream) {
    const float* Q = (const float*)d_in[0];
    const float* K = (const float*)d_in[1];
    const float* V = (const float*)d_in[2];
    const int* cuq = (const int*)d_in[3];
    const int* cuk = (const int*)d_in[4];
    float* O = (float*)d_out;

    int T = in_sizes[0] / (H * D);
    int nQT = (T + BQ - 1) / BQ;
    dim3 grid(nQT * H), block(NT);
    hipLaunchKernelGGL(varlen_attn_mfma, grid, block, 0, stream, Q, K, V, cuq, cuk, O, T);
}

// Round 3
// 145.531 us; speedup vs baseline: 2.5308x; 1.1658x over previous
//
#include <hip/hip_runtime.h>

// VarlenAttention MI355X — round 3: bf16 MFMA flash kernel + K/V pre-conversion
// pre-pass. Hot loop stages pre-converted bf16 K (head-major) and V^T via
// aligned b128 copies with one-chunk-ahead register prefetch.
constexpr int NSEG = 8;
constexpr int H    = 16;
constexpr int D    = 64;
constexpr int BQ   = 64;   // q rows per block
constexpr int BK   = 64;   // keys per chunk
constexpr int NT   = 256;
constexpr int LDK  = D  + 8;   // 144B rows (16B-aligned), bank-spread
constexpr int LDV  = BK + 8;
constexpr int LDP  = BK + 8;

typedef __attribute__((ext_vector_type(8))) short short8v;
typedef __attribute__((ext_vector_type(4))) short short4v;
typedef __attribute__((ext_vector_type(4))) float floatx4;

__device__ inline short f2bf(float f) {  // RNE fp32 -> bf16
    union { float f; unsigned u; } x; x.f = f;
    unsigned r = x.u + 0x7FFFu + ((x.u >> 16) & 1u);
    return (short)(r >> 16);
}

// ---------------- pre-pass: K -> Kb[h][t][d] bf16, V -> Vb[h][d][t] bf16 ----
__global__ __launch_bounds__(NT)
void prepass_kv(const float* __restrict__ K, const float* __restrict__ V,
                short* __restrict__ Kb, short* __restrict__ Vb, int T)
{
    __shared__ short sVT[D][LDK];
    const int tid = threadIdx.x;
    const int nCh = T >> 6;
    const int h  = blockIdx.x / nCh;
    const int t0 = (blockIdx.x % nCh) << 6;
    #pragma unroll
    for (int it = 0; it < 2; ++it) {
        int s  = tid + it * NT;          // 0..511
        int tl = s >> 3;                 // local token 0..63
        int d8 = (s & 7) << 3;
        int t  = t0 + tl;
        const float* kp = K + ((size_t)t * H + h) * D + d8;
        float4 a = *(const float4*)kp;
        float4 b = *(const float4*)(kp + 4);
        short8v ks;
        ks[0]=f2bf(a.x); ks[1]=f2bf(a.y); ks[2]=f2bf(a.z); ks[3]=f2bf(a.w);
        ks[4]=f2bf(b.x); ks[5]=f2bf(b.y); ks[6]=f2bf(b.z); ks[7]=f2bf(b.w);
        *(short8v*)&Kb[((size_t)h * T + t) * D + d8] = ks;
        const float* vp = V + ((size_t)t * H + h) * D + d8;
        float4 c = *(const float4*)vp;
        float4 e = *(const float4*)(vp + 4);
        sVT[d8+0][tl]=f2bf(c.x); sVT[d8+1][tl]=f2bf(c.y);
        sVT[d8+2][tl]=f2bf(c.z); sVT[d8+3][tl]=f2bf(c.w);
        sVT[d8+4][tl]=f2bf(e.x); sVT[d8+5][tl]=f2bf(e.y);
        sVT[d8+6][tl]=f2bf(e.z); sVT[d8+7][tl]=f2bf(e.w);
    }
    __syncthreads();
    #pragma unroll
    for (int it = 0; it < 2; ++it) {
        int s  = tid + it * NT;
        int d  = s >> 3;
        int t8 = (s & 7) << 3;
        *(short8v*)&Vb[((size_t)h * D + d) * T + t0 + t8] = *(const short8v*)&sVT[d][t8];
    }
}

// ---------------- main flash kernel (pre-converted K/V) ---------------------
__global__ __launch_bounds__(NT)
void varlen_attn_mfma2(const float* __restrict__ Q,
                       const short* __restrict__ Kb, const short* __restrict__ Vb,
                       const int* __restrict__ cuq, const int* __restrict__ cuk,
                       float* __restrict__ O, int T)
{
    __shared__ short sK[BK][LDK];        // (key, d)
    __shared__ short sVT[D][LDV];        // (d, key)
    __shared__ short sP[4][16][LDP];     // per-wave (qrow, key)
    __shared__ int   sSegK[BK];
    __shared__ int   sCuQ[NSEG + 1], sCuK[NSEG + 1];

    const int tid  = threadIdx.x;
    const int lane = tid & 63;
    const int w    = tid >> 6;
    const int quad = lane >> 4;
    const int l15  = lane & 15;
    const int h    = blockIdx.x % H;
    const int t0   = (blockIdx.x / H) * BQ;

    if (tid <= NSEG) { sCuQ[tid] = cuq[tid]; sCuK[tid] = cuk[tid]; }
    __syncthreads();

    // Q A-frags, pre-scaled by 0.125 (exact in bf16)
    int qrow = t0 + 16 * w + l15; if (qrow >= T) qrow = T - 1;
    const float* qp = Q + ((size_t)qrow * H + h) * D + quad * 8;
    short8v aQ0, aQ1;
    {
        float4 q0 = *(const float4*)(qp);
        float4 q1 = *(const float4*)(qp + 4);
        float4 q2 = *(const float4*)(qp + 32);
        float4 q3 = *(const float4*)(qp + 36);
        aQ0[0] = f2bf(q0.x * 0.125f); aQ0[1] = f2bf(q0.y * 0.125f);
        aQ0[2] = f2bf(q0.z * 0.125f); aQ0[3] = f2bf(q0.w * 0.125f);
        aQ0[4] = f2bf(q1.x * 0.125f); aQ0[5] = f2bf(q1.y * 0.125f);
        aQ0[6] = f2bf(q1.z * 0.125f); aQ0[7] = f2bf(q1.w * 0.125f);
        aQ1[0] = f2bf(q2.x * 0.125f); aQ1[1] = f2bf(q2.y * 0.125f);
        aQ1[2] = f2bf(q2.z * 0.125f); aQ1[3] = f2bf(q2.w * 0.125f);
        aQ1[4] = f2bf(q3.x * 0.125f); aQ1[5] = f2bf(q3.y * 0.125f);
        aQ1[6] = f2bf(q3.z * 0.125f); aQ1[7] = f2bf(q3.w * 0.125f);
    }

    int segq[4];
    #pragma unroll
    for (int r = 0; r < 4; ++r) {
        int t = t0 + 16 * w + quad * 4 + r; if (t >= T) t = T - 1;
        int s = 0;
        while (s < NSEG - 1 && t >= sCuQ[s + 1]) ++s;
        segq[r] = s;
    }

    int k_start, k_end;
    {
        int tA = t0; if (tA >= T) tA = T - 1;
        int tB = t0 + BQ - 1; if (tB >= T) tB = T - 1;
        int sA = 0; while (sA < NSEG - 1 && tA >= sCuQ[sA + 1]) ++sA;
        int sB = 0; while (sB < NSEG - 1 && tB >= sCuQ[sB + 1]) ++sB;
        k_start = sCuK[sA];
        k_end   = sCuK[sB + 1];
    }

    const short* Kbh = Kb + (size_t)h * T * D;
    const short* Vbh = Vb + (size_t)h * D * T;
    const int key0 = tid >> 3;        // 0..31
    const int e8   = (tid & 7) << 3;  // 0..56

    floatx4 o[4];
    #pragma unroll
    for (int nt = 0; nt < 4; ++nt) o[nt] = (floatx4){0.f, 0.f, 0.f, 0.f};
    float m_r[4], l_r[4];
    #pragma unroll
    for (int r = 0; r < 4; ++r) { m_r[r] = -1e30f; l_r[r] = 0.f; }

    const int kc0 = k_start & ~(BK - 1);   // 64-aligned chunks (extras masked)

    short8v rb0, rb1, rb2, rb3;
    rb0 = *(const short8v*)(Kbh + (size_t)(kc0 + key0)      * D + e8);
    rb1 = *(const short8v*)(Kbh + (size_t)(kc0 + 32 + key0) * D + e8);
    rb2 = *(const short8v*)(Vbh + (size_t)key0        * T + kc0 + e8);
    rb3 = *(const short8v*)(Vbh + (size_t)(32 + key0) * T + kc0 + e8);

    for (int kc = kc0; kc < k_end; kc += BK) {
        __syncthreads();   // previous chunk's LDS reads complete
        *(short8v*)&sK[key0][e8]       = rb0;
        *(short8v*)&sK[32 + key0][e8]  = rb1;
        *(short8v*)&sVT[key0][e8]      = rb2;
        *(short8v*)&sVT[32 + key0][e8] = rb3;
        if (tid < BK) {
            int kt = kc + tid;                   // kt < T guaranteed
            int s = 0;
            while (s < NSEG - 1 && kt >= sCuK[s + 1]) ++s;
            sSegK[tid] = s;
        }
        __syncthreads();

        // fire next chunk's loads (overlap with compute below)
        int kn = kc + BK;
        if (kn < k_end) {
            rb0 = *(const short8v*)(Kbh + (size_t)(kn + key0)      * D + e8);
            rb1 = *(const short8v*)(Kbh + (size_t)(kn + 32 + key0) * D + e8);
            rb2 = *(const short8v*)(Vbh + (size_t)key0        * T + kn + e8);
            rb3 = *(const short8v*)(Vbh + (size_t)(32 + key0) * T + kn + e8);
        }

        // ---- S = Q K^T
        floatx4 sacc[4];
        #pragma unroll
        for (int nt = 0; nt < 4; ++nt) {
            sacc[nt] = (floatx4){0.f, 0.f, 0.f, 0.f};
            short8v b0 = *(const short8v*)&sK[nt * 16 + l15][quad * 8];
            short8v b1 = *(const short8v*)&sK[nt * 16 + l15][32 + quad * 8];
            sacc[nt] = __builtin_amdgcn_mfma_f32_16x16x32_bf16(aQ0, b0, sacc[nt], 0, 0, 0);
            sacc[nt] = __builtin_amdgcn_mfma_f32_16x16x32_bf16(aQ1, b1, sacc[nt], 0, 0, 0);
        }

        // ---- mask + online softmax
        int segk[4];
        #pragma unroll
        for (int nt = 0; nt < 4; ++nt) segk[nt] = sSegK[nt * 16 + l15];

        float sc[4][4];
        #pragma unroll
        for (int nt = 0; nt < 4; ++nt)
            #pragma unroll
            for (int r = 0; r < 4; ++r)
                sc[nt][r] = (segk[nt] == segq[r]) ? sacc[nt][r] : -1e30f;

        float mx[4];
        #pragma unroll
        for (int r = 0; r < 4; ++r)
            mx[r] = fmaxf(fmaxf(sc[0][r], sc[1][r]), fmaxf(sc[2][r], sc[3][r]));
        #pragma unroll
        for (int off = 1; off < 16; off <<= 1)
            #pragma unroll
            for (int r = 0; r < 4; ++r)
                mx[r] = fmaxf(mx[r], __shfl_xor(mx[r], off));

        float alpha[4];
        #pragma unroll
        for (int r = 0; r < 4; ++r) {
            float m_new = fmaxf(m_r[r], mx[r]);
            alpha[r] = __expf(m_r[r] - m_new);
            m_r[r] = m_new;
        }

        float psum[4] = {0.f, 0.f, 0.f, 0.f};
        #pragma unroll
        for (int nt = 0; nt < 4; ++nt)
            #pragma unroll
            for (int r = 0; r < 4; ++r) {
                float p = (sc[nt][r] > -1e29f) ? __expf(sc[nt][r] - m_r[r]) : 0.f;
                psum[r] += p;
                sP[w][quad * 4 + r][nt * 16 + l15] = f2bf(p);
            }
        #pragma unroll
        for (int off = 1; off < 16; off <<= 1)
            #pragma unroll
            for (int r = 0; r < 4; ++r)
                psum[r] += __shfl_xor(psum[r], off);
        #pragma unroll
        for (int r = 0; r < 4; ++r)
            l_r[r] = l_r[r] * alpha[r] + psum[r];

        #pragma unroll
        for (int nt = 0; nt < 4; ++nt)
            #pragma unroll
            for (int r = 0; r < 4; ++r)
                o[nt][r] *= alpha[r];

        // ---- O += P V (in-wave LDS roundtrip for the layout transform)
        short8v aP0 = *(const short8v*)&sP[w][l15][quad * 8];
        short8v aP1 = *(const short8v*)&sP[w][l15][32 + quad * 8];
        #pragma unroll
        for (int nt = 0; nt < 4; ++nt) {
            short8v b0 = *(const short8v*)&sVT[nt * 16 + l15][quad * 8];
            short8v b1 = *(const short8v*)&sVT[nt * 16 + l15][32 + quad * 8];
            o[nt] = __builtin_amdgcn_mfma_f32_16x16x32_bf16(aP0, b0, o[nt], 0, 0, 0);
            o[nt] = __builtin_amdgcn_mfma_f32_16x16x32_bf16(aP1, b1, o[nt], 0, 0, 0);
        }
    }

    #pragma unroll
    for (int r = 0; r < 4; ++r) {
        int trow = t0 + 16 * w + quad * 4 + r;
        if (trow < T) {
            float linv = 1.0f / l_r[r];
            float* op = O + ((size_t)trow * H + h) * D + l15;
            #pragma unroll
            for (int nt = 0; nt < 4; ++nt)
                op[nt * 16] = o[nt][r] * linv;
        }
    }
}

// ---------------- fallback (round-2 kernel) if ws too small -----------------
__global__ __launch_bounds__(NT)
void varlen_attn_fb(const float* __restrict__ Q, const float* __restrict__ K,
                    const float* __restrict__ V, const int* __restrict__ cuq,
                    const int* __restrict__ cuk, float* __restrict__ O, int T)
{
    __shared__ short sK[BK][LDK];
    __shared__ short sVT[D][LDV];
    __shared__ short sP[4][16][LDP];
    __shared__ int   sSegK[BK];
    __shared__ int   sCuQ[NSEG + 1], sCuK[NSEG + 1];

    const int tid  = threadIdx.x;
    const int lane = tid & 63;
    const int w    = tid >> 6;
    const int quad = lane >> 4;
    const int l15  = lane & 15;
    const int h    = blockIdx.x % H;
    const int t0   = (blockIdx.x / H) * BQ;

    if (tid <= NSEG) { sCuQ[tid] = cuq[tid]; sCuK[tid] = cuk[tid]; }
    __syncthreads();

    int qrow = t0 + 16 * w + l15; if (qrow >= T) qrow = T - 1;
    const float* qp = Q + ((size_t)qrow * H + h) * D + quad * 8;
    short8v aQ0, aQ1;
    {
        float4 q0 = *(const float4*)(qp);
        float4 q1 = *(const float4*)(qp + 4);
        float4 q2 = *(const float4*)(qp + 32);
        float4 q3 = *(const float4*)(qp + 36);
        aQ0[0] = f2bf(q0.x * 0.125f); aQ0[1] = f2bf(q0.y * 0.125f);
        aQ0[2] = f2bf(q0.z * 0.125f); aQ0[3] = f2bf(q0.w * 0.125f);
        aQ0[4] = f2bf(q1.x * 0.125f); aQ0[5] = f2bf(q1.y * 0.125f);
        aQ0[6] = f2bf(q1.z * 0.125f); aQ0[7] = f2bf(q1.w * 0.125f);
        aQ1[0] = f2bf(q2.x * 0.125f); aQ1[1] = f2bf(q2.y * 0.125f);
        aQ1[2] = f2bf(q2.z * 0.125f); aQ1[3] = f2bf(q2.w * 0.125f);
        aQ1[4] = f2bf(q3.x * 0.125f); aQ1[5] = f2bf(q3.y * 0.125f);
        aQ1[6] = f2bf(q3.z * 0.125f); aQ1[7] = f2bf(q3.w * 0.125f);
    }

    int segq[4];
    #pragma unroll
    for (int r = 0; r < 4; ++r) {
        int t = t0 + 16 * w + quad * 4 + r; if (t >= T) t = T - 1;
        int s = 0;
        while (s < NSEG - 1 && t >= sCuQ[s + 1]) ++s;
        segq[r] = s;
    }

    int k_start, k_end;
    {
        int tA = t0; if (tA >= T) tA = T - 1;
        int tB = t0 + BQ - 1; if (tB >= T) tB = T - 1;
        int sA = 0; while (sA < NSEG - 1 && tA >= sCuQ[sA + 1]) ++sA;
        int sB = 0; while (sB < NSEG - 1 && tB >= sCuQ[sB + 1]) ++sB;
        k_start = sCuK[sA];
        k_end   = sCuK[sB + 1];
    }

    floatx4 o[4];
    #pragma unroll
    for (int nt = 0; nt < 4; ++nt) o[nt] = (floatx4){0.f, 0.f, 0.f, 0.f};
    float m_r[4], l_r[4];
    #pragma unroll
    for (int r = 0; r < 4; ++r) { m_r[r] = -1e30f; l_r[r] = 0.f; }

    for (int kc = k_start; kc < k_end; kc += BK) {
        __syncthreads();
        for (int i = tid; i < BK * D / 4; i += NT) {
            int k = i >> 4;
            int c = (i & 15) << 2;
            int kt = kc + k;
            float4 kv = {0.f, 0.f, 0.f, 0.f}, vv = {0.f, 0.f, 0.f, 0.f};
            if (kt < k_end) {
                kv = *(const float4*)&K[((size_t)kt * H + h) * D + c];
                vv = *(const float4*)&V[((size_t)kt * H + h) * D + c];
            }
            short4v ks;
            ks.x = f2bf(kv.x); ks.y = f2bf(kv.y); ks.z = f2bf(kv.z); ks.w = f2bf(kv.w);
            *(short4v*)&sK[k][c] = ks;
            sVT[c + 0][k] = f2bf(vv.x);
            sVT[c + 1][k] = f2bf(vv.y);
            sVT[c + 2][k] = f2bf(vv.z);
            sVT[c + 3][k] = f2bf(vv.w);
        }
        if (tid < BK) {
            int kt = kc + tid;
            int s = -1;
            if (kt < k_end) { s = 0; while (s < NSEG - 1 && kt >= sCuK[s + 1]) ++s; }
            sSegK[tid] = s;
        }
        __syncthreads();

        floatx4 sacc[4];
        #pragma unroll
        for (int nt = 0; nt < 4; ++nt) {
            sacc[nt] = (floatx4){0.f, 0.f, 0.f, 0.f};
            short8v b0 = *(const short8v*)&sK[nt * 16 + l15][quad * 8];
            short8v b1 = *(const short8v*)&sK[nt * 16 + l15][32 + quad * 8];
            sacc[nt] = __builtin_amdgcn_mfma_f32_16x16x32_bf16(aQ0, b0, sacc[nt], 0, 0, 0);
            sacc[nt] = __builtin_amdgcn_mfma_f32_16x16x32_bf16(aQ1, b1, sacc[nt], 0, 0, 0);
        }

        int segk[4];
        #pragma unroll
        for (int nt = 0; nt < 4; ++nt) segk[nt] = sSegK[nt * 16 + l15];

        float sc[4][4];
        #pragma unroll
        for (int nt = 0; nt < 4; ++nt)
            #pragma unroll
            for (int r = 0; r < 4; ++r)
                sc[nt][r] = (segk[nt] == segq[r]) ? sacc[nt][r] : -1e30f;

        float mx[4];
        #pragma unroll
        for (int r = 0; r < 4; ++r)
            mx[r] = fmaxf(fmaxf(sc[0][r], sc[1][r]), fmaxf(sc[2][r], sc[3][r]));
        #pragma unroll
        for (int off = 1; off < 16; off <<= 1)
            #pragma unroll
            for (int r = 0; r < 4; ++r)
                mx[r] = fmaxf(mx[r], __shfl_xor(mx[r], off));

        float alpha[4];
        #pragma unroll
        for (int r = 0; r < 4; ++r) {
            float m_new = fmaxf(m_r[r], mx[r]);
            alpha[r] = __expf(m_r[r] - m_new);
            m_r[r] = m_new;
        }

        float psum[4] = {0.f, 0.f, 0.f, 0.f};
        #pragma unroll
        for (int nt = 0; nt < 4; ++nt)
            #pragma unroll
            for (int r = 0; r < 4; ++r) {
                float p = (sc[nt][r] > -1e29f) ? __expf(sc[nt][r] - m_r[r]) : 0.f;
                psum[r] += p;
                sP[w][quad * 4 + r][nt * 16 + l15] = f2bf(p);
            }
        #pragma unroll
        for (int off = 1; off < 16; off <<= 1)
            #pragma unroll
            for (int r = 0; r < 4; ++r)
                psum[r] += __shfl_xor(psum[r], off);
        #pragma unroll
        for (int r = 0; r < 4; ++r)
            l_r[r] = l_r[r] * alpha[r] + psum[r];

        #pragma unroll
        for (int nt = 0; nt < 4; ++nt)
            #pragma unroll
            for (int r = 0; r < 4; ++r)
                o[nt][r] *= alpha[r];

        short8v aP0 = *(const short8v*)&sP[w][l15][quad * 8];
        short8v aP1 = *(const short8v*)&sP[w][l15][32 + quad * 8];
        #pragma unroll
        for (int nt = 0; nt < 4; ++nt) {
            short8v b0 = *(const short8v*)&sVT[nt * 16 + l15][quad * 8];
            short8v b1 = *(const short8v*)&sVT[nt * 16 + l15][32 + quad * 8];
            o[nt] = __builtin_amdgcn_mfma_f32_16x16x32_bf16(aP0, b0, o[nt], 0, 0, 0);
            o[nt] = __builtin_amdgcn_mfma_f32_16x16x32_bf16(aP1, b1, o[nt], 0, 0, 0);
        }
    }

    #pragma unroll
    for (int r = 0; r < 4; ++r) {
        int trow = t0 + 16 * w + quad * 4 + r;
        if (trow < T) {
            float linv = 1.0f / l_r[r];
            float* op = O + ((size_t)trow * H + h) * D + l15;
            #pragma unroll
            for (int nt = 0; nt < 4; ++nt)
                op[nt * 16] = o[nt][r] * linv;
        }
    }
}

extern "C" void kernel_launch(void* const* d_in, const int* in_sizes, int n_in,
                              void* d_out, int out_size, void* d_ws, size_t ws_size,
                              hipStream_t stream) {
    const float* Q = (const float*)d_in[0];
    const float* K = (const float*)d_in[1];
    const float* V = (const float*)d_in[2];
    const int* cuq = (const int*)d_in[3];
    const int* cuk = (const int*)d_in[4];
    float* O = (float*)d_out;

    int T = in_sizes[0] / (H * D);
    int nQT = (T + BQ - 1) / BQ;
    size_t need = (size_t)2 * H * T * D * sizeof(short);

    if (ws_size >= need && (T & 63) == 0) {
        short* Kb = (short*)d_ws;
        short* Vb = Kb + (size_t)H * T * D;
        hipLaunchKernelGGL(prepass_kv, dim3(H * (T >> 6)), dim3(NT), 0, stream,
                           K, V, Kb, Vb, T);
        hipLaunchKernelGGL(varlen_attn_mfma2, dim3(nQT * H), dim3(NT), 0, stream,
                           Q, Kb, Vb, cuq, cuk, O, T);
    } else {
        hipLaunchKernelGGL(varlen_attn_fb, dim3(nQT * H), dim3(NT), 0, stream,
                           Q, K, V, cuq, cuk, O, T);
    }
}